// Round 1
// baseline (278.316 us; speedup 1.0000x reference)
//
#include <hip/hip_runtime.h>
#include <math.h>

#define N_NODES_C 100000
#define N_EDGES_C 600000
#define DIM 128

// -------- Kernel 1: expmap0 + Lorentz factor ------------------------------
// gx[n,d]   = gamma_n * x_hyp[n,d]
// gm1[n]    = gamma_n - 1
__global__ void __launch_bounds__(128)
expmap_gamma_kernel(const float* __restrict__ x,
                    float* __restrict__ gx,
                    float* __restrict__ gm1) {
    const int node = blockIdx.x;
    const int d = threadIdx.x;
    const float v = x[node * DIM + d];

    // block reduce sum of squares (128 threads = 2 waves)
    __shared__ float red[2];
    float s = v * v;
    #pragma unroll
    for (int off = 32; off > 0; off >>= 1) s += __shfl_down(s, off, 64);
    if ((d & 63) == 0) red[d >> 6] = s;
    __syncthreads();
    const float ss = red[0] + red[1];

    float un = sqrtf(ss);
    un = fmaxf(un, 1e-15f);                 // _safe_norm
    const float th = tanhf(un);             // sqrt(c)=1
    const float xh = th * v / un;           // x_hyp element
    // ||x_hyp||^2 = th^2 * ss / un^2 (exact composition of reference ops)
    const float ssh = th * th * (ss / (un * un));
    const float gamma = 2.0f / fmaxf(1.0f - ssh, 1e-15f);
    gx[node * DIM + d] = gamma * xh;
    if (d == 0) gm1[node] = gamma - 1.0f;
}

// -------- Kernel 2: CSR row_ptr from sorted rows via binary search --------
__global__ void rowptr_kernel(const int* __restrict__ rows,
                              int* __restrict__ row_ptr) {
    const int i = blockIdx.x * blockDim.x + threadIdx.x;
    if (i > N_NODES_C) return;
    int lo = 0, hi = N_EDGES_C;
    while (lo < hi) {
        int mid = (lo + hi) >> 1;
        if (rows[mid] < i) lo = mid + 1; else hi = mid;
    }
    row_ptr[i] = lo;
}

// -------- Kernel 3: segment-sum + gyromidpoint + logmap0 ------------------
__global__ void __launch_bounds__(128)
agg_kernel(const float* __restrict__ gx,
           const float* __restrict__ gm1,
           const int* __restrict__ cols,
           const float* __restrict__ vals,
           const int* __restrict__ row_ptr,
           float* __restrict__ out) {
    const int row = blockIdx.x;
    const int d = threadIdx.x;
    const int e0 = row_ptr[row];
    const int e1 = row_ptr[row + 1];

    float num = 0.0f;
    float den = 0.0f;   // every thread accumulates the same scalar (broadcast loads)
    for (int e = e0; e < e1; ++e) {
        const int c = cols[e];
        const float w = vals[e];
        num = fmaf(w, gx[c * DIM + d], num);
        den = fmaf(w, gm1[c], den);
    }

    // sign-preserving clamp_abs(den, 1e-10)
    const float sden = (den >= 0.0f) ? 1.0f : -1.0f;
    den = sden * fmaxf(fabsf(den), 1e-10f);
    const float t = num / den;              // two_mean element

    // block reduce ||t||^2
    __shared__ float red[2];
    float s = t * t;
    #pragma unroll
    for (int off = 32; off > 0; off >>= 1) s += __shfl_down(s, off, 64);
    if ((d & 63) == 0) red[d >> 6] = s;
    __syncthreads();
    const float ss = red[0] + red[1];

    const float tn = sqrtf(ss);
    const float vn = fmaxf(tn, 1e-15f);     // _safe_norm(two_mean)
    // mobius_scalar_mul(0.5, t): m = tanh(0.5*artanh(clip(vn))) * t / vn
    const float ac = fminf(fmaxf(vn, -1.0f + 1e-7f), 1.0f - 1e-7f);
    const float tanhval = tanhf(0.5f * atanhf(ac));   // >= 0
    const float m_scale = tanhval / vn;               // m = m_scale * t
    // logmap0(m): ||m|| = tanhval * tn / vn
    const float pn = fmaxf(tanhval * tn / vn, 1e-15f);
    const float pc = fminf(fmaxf(pn, -1.0f + 1e-7f), 1.0f - 1e-7f);
    const float o_scale = (atanhf(pc) / pn) * m_scale;

    out[row * DIM + d] = o_scale * t;
}

extern "C" void kernel_launch(void* const* d_in, const int* in_sizes, int n_in,
                              void* d_out, int out_size, void* d_ws, size_t ws_size,
                              hipStream_t stream) {
    const float* x    = (const float*)d_in[0];
    const int*   rows = (const int*)d_in[1];
    const int*   cols = (const int*)d_in[2];
    const float* vals = (const float*)d_in[3];
    float* out = (float*)d_out;

    // workspace layout
    float* gx  = (float*)d_ws;                                  // N*D floats = 51.2 MB
    float* gm1 = gx + (size_t)N_NODES_C * DIM;                  // N floats
    int* row_ptr = (int*)(gm1 + N_NODES_C);                     // N+1 ints

    expmap_gamma_kernel<<<N_NODES_C, 128, 0, stream>>>(x, gx, gm1);
    rowptr_kernel<<<(N_NODES_C + 1 + 255) / 256, 256, 0, stream>>>(rows, row_ptr);
    agg_kernel<<<N_NODES_C, 128, 0, stream>>>(gx, gm1, cols, vals, row_ptr, out);
}

// Round 2
// 166.522 us; speedup vs baseline: 1.6713x; 1.6713x over previous
//
#include <hip/hip_runtime.h>
#include <math.h>

#define N_NODES_C 100000
#define N_EDGES_C 600000
#define DIM 128
#define ROWS_PER_BLOCK 8   // 256 threads, 32 lanes (one float4 slice each) per row

// -------- Kernel 1: per-node scalars ---------------------------------------
// s_n  = gamma_n * tanh(||x_n||) / ||x_n||      (so  gx[n,d] = s_n * x[n,d])
// gm1_n = gamma_n - 1
// packed as float2 {s, gm1}
__global__ void __launch_bounds__(256)
node_scale_kernel(const float4* __restrict__ x4,
                  float2* __restrict__ sg) {
    const int grp  = threadIdx.x >> 5;
    const int lane = threadIdx.x & 31;
    const int node = blockIdx.x * ROWS_PER_BLOCK + grp;

    const float4 v = x4[(size_t)node * 32 + lane];
    float ss = v.x * v.x + v.y * v.y + v.z * v.z + v.w * v.w;
    #pragma unroll
    for (int m = 16; m > 0; m >>= 1) ss += __shfl_xor(ss, m, 64);

    const float un = fmaxf(sqrtf(ss), 1e-15f);        // _safe_norm
    // tanh(un) = (e^{2u}-1)/(e^{2u}+1), hardware exp
    const float e2 = __expf(2.0f * un);
    const float th = (e2 - 1.0f) / (e2 + 1.0f);
    const float ssh = th * th;                        // ||x_hyp||^2
    const float gamma = 2.0f / fmaxf(1.0f - ssh, 1e-15f);
    if (lane == 0) sg[node] = make_float2(gamma * th / un, gamma - 1.0f);
}

// -------- Kernel 2: CSR row_ptr from sorted rows via binary search ---------
__global__ void rowptr_kernel(const int* __restrict__ rows,
                              int* __restrict__ row_ptr) {
    const int i = blockIdx.x * blockDim.x + threadIdx.x;
    if (i > N_NODES_C) return;
    int lo = 0, hi = N_EDGES_C;
    while (lo < hi) {
        int mid = (lo + hi) >> 1;
        if (rows[mid] < i) lo = mid + 1; else hi = mid;
    }
    row_ptr[i] = lo;
}

// -------- Kernel 3: segment-sum + gyromidpoint + logmap0 -------------------
__global__ void __launch_bounds__(256)
agg_kernel(const float4* __restrict__ x4,
           const float2* __restrict__ sg,
           const int* __restrict__ cols,
           const float* __restrict__ vals,
           const int* __restrict__ row_ptr,
           float4* __restrict__ out4) {
    const int grp  = threadIdx.x >> 5;
    const int lane = threadIdx.x & 31;
    const int row  = blockIdx.x * ROWS_PER_BLOCK + grp;

    const int e0 = row_ptr[row];
    const int e1 = row_ptr[row + 1];

    float4 num = make_float4(0.f, 0.f, 0.f, 0.f);
    float den = 0.0f;   // identical across the 32 lanes of the group
    for (int e = e0; e < e1; ++e) {
        const int   c  = cols[e];
        const float w  = vals[e];
        const float2 s2 = sg[c];
        const float ws = w * s2.x;
        den = fmaf(w, s2.y, den);
        const float4 xv = x4[(size_t)c * 32 + lane];
        num.x = fmaf(ws, xv.x, num.x);
        num.y = fmaf(ws, xv.y, num.y);
        num.z = fmaf(ws, xv.z, num.z);
        num.w = fmaf(ws, xv.w, num.w);
    }

    // sign-preserving clamp_abs(den, 1e-10)
    const float sden = (den >= 0.0f) ? 1.0f : -1.0f;
    den = sden * fmaxf(fabsf(den), 1e-10f);
    float4 t;
    t.x = num.x / den;
    t.y = num.y / den;
    t.z = num.z / den;
    t.w = num.w / den;

    // group-reduce ||t||^2 across the 32 lanes
    float ss = t.x * t.x + t.y * t.y + t.z * t.z + t.w * t.w;
    #pragma unroll
    for (int m = 16; m > 0; m >>= 1) ss += __shfl_xor(ss, m, 64);

    const float tn = sqrtf(ss);
    const float vn = fmaxf(tn, 1e-15f);               // _safe_norm(two_mean)
    const float ac = fminf(vn, 1.0f - 1e-7f);         // artanh clip (vn >= 0)
    // tanh(0.5*artanh(ac)) = ac / (1 + sqrt(1 - ac^2))  -- exact identity
    const float tanhval = ac / (1.0f + sqrtf(fmaxf(1.0f - ac * ac, 0.0f)));
    const float m_scale = tanhval / vn;               // m = m_scale * t
    // logmap0(m): ||m|| = tanhval * tn / vn
    const float pn = fmaxf(tanhval * (tn / vn), 1e-15f);
    const float pc = fminf(pn, 1.0f - 1e-7f);
    // atanh(pc) = 0.5 * ln((1+pc)/(1-pc)), hardware log
    const float at = 0.5f * __logf((1.0f + pc) / (1.0f - pc));
    const float o_scale = (at / pn) * m_scale;

    float4 o;
    o.x = o_scale * t.x;
    o.y = o_scale * t.y;
    o.z = o_scale * t.z;
    o.w = o_scale * t.w;
    out4[(size_t)row * 32 + lane] = o;
}

extern "C" void kernel_launch(void* const* d_in, const int* in_sizes, int n_in,
                              void* d_out, int out_size, void* d_ws, size_t ws_size,
                              hipStream_t stream) {
    const float4* x4   = (const float4*)d_in[0];
    const int*    rows = (const int*)d_in[1];
    const int*    cols = (const int*)d_in[2];
    const float*  vals = (const float*)d_in[3];
    float4* out4 = (float4*)d_out;

    // workspace layout
    float2* sg = (float2*)d_ws;                         // N float2 = 800 KB
    int* row_ptr = (int*)(sg + N_NODES_C);              // N+1 ints

    node_scale_kernel<<<N_NODES_C / ROWS_PER_BLOCK, 256, 0, stream>>>(x4, sg);
    rowptr_kernel<<<(N_NODES_C + 1 + 255) / 256, 256, 0, stream>>>(rows, row_ptr);
    agg_kernel<<<N_NODES_C / ROWS_PER_BLOCK, 256, 0, stream>>>(x4, sg, cols, vals, row_ptr, out4);
}

// Round 3
// 159.312 us; speedup vs baseline: 1.7470x; 1.0453x over previous
//
#include <hip/hip_runtime.h>
#include <math.h>

#define N_NODES_C 100000
#define N_EDGES_C 600000
#define ROWS_PER_BLOCK 8   // 256 threads, 32 lanes (one float4 slice each) per row

// -------- Kernel 1: per-node scalars ---------------------------------------
// sg[n] = { gamma_n * tanh(||x_n||)/||x_n|| , gamma_n - 1 }
__global__ void __launch_bounds__(256)
node_scale_kernel(const float4* __restrict__ x4,
                  float2* __restrict__ sg) {
    const int grp  = threadIdx.x >> 5;
    const int lane = threadIdx.x & 31;
    const int node = blockIdx.x * ROWS_PER_BLOCK + grp;

    const float4 v = x4[(size_t)node * 32 + lane];
    float ss = v.x * v.x + v.y * v.y + v.z * v.z + v.w * v.w;
    #pragma unroll
    for (int m = 16; m > 0; m >>= 1) ss += __shfl_xor(ss, m, 64);

    const float un = fmaxf(sqrtf(ss), 1e-15f);        // _safe_norm
    const float e2 = __expf(2.0f * un);               // tanh via hw exp
    const float th = (e2 - 1.0f) / (e2 + 1.0f);
    const float gamma = 2.0f / fmaxf(1.0f - th * th, 1e-15f);
    if (lane == 0) sg[node] = make_float2(gamma * th / un, gamma - 1.0f);
}

// -------- Kernel 2: CSR row_ptr from sorted rows via binary search ---------
__global__ void rowptr_kernel(const int* __restrict__ rows,
                              int* __restrict__ row_ptr) {
    const int i = blockIdx.x * blockDim.x + threadIdx.x;
    if (i > N_NODES_C) return;
    int lo = 0, hi = N_EDGES_C;
    while (lo < hi) {
        int mid = (lo + hi) >> 1;
        if (rows[mid] < i) lo = mid + 1; else hi = mid;
    }
    row_ptr[i] = lo;
}

// -------- Kernel 3: segment-sum + gyromidpoint + logmap0 -------------------
__global__ void __launch_bounds__(256)
agg_kernel(const float4* __restrict__ x4,
           const float2* __restrict__ sg,
           const int* __restrict__ cols,
           const float* __restrict__ vals,
           const int* __restrict__ row_ptr,
           float4* __restrict__ out4) {
    const int grp  = threadIdx.x >> 5;
    const int lane = threadIdx.x & 31;
    const int row  = blockIdx.x * ROWS_PER_BLOCK + grp;

    const int e0  = row_ptr[row];
    const int deg = row_ptr[row + 1] - e0;

    float4 num = make_float4(0.f, 0.f, 0.f, 0.f);
    float den_l = 0.0f;

    for (int base = 0; base < deg; base += 32) {
        const int m = min(32, deg - base);
        // cooperative preload: lane l owns edge e0+base+l
        int   myc  = 0;
        float myws = 0.0f;
        if (lane < m) {
            const int e = e0 + base + lane;
            const int c = cols[e];
            const float w = vals[e];
            const float2 s2 = sg[c];
            myc   = c;
            myws  = w * s2.x;                 // weight * node scale
            den_l = fmaf(w, s2.y, den_l);     // den accumulates here, not in loop
        }

        int j = 0;
        for (; j + 4 <= m; j += 4) {          // 4 gathers in flight
            const int   c0 = __shfl(myc,  j + 0, 32);
            const int   c1 = __shfl(myc,  j + 1, 32);
            const int   c2 = __shfl(myc,  j + 2, 32);
            const int   c3 = __shfl(myc,  j + 3, 32);
            const float w0 = __shfl(myws, j + 0, 32);
            const float w1 = __shfl(myws, j + 1, 32);
            const float w2 = __shfl(myws, j + 2, 32);
            const float w3 = __shfl(myws, j + 3, 32);
            const float4 v0 = x4[(size_t)c0 * 32 + lane];
            const float4 v1 = x4[(size_t)c1 * 32 + lane];
            const float4 v2 = x4[(size_t)c2 * 32 + lane];
            const float4 v3 = x4[(size_t)c3 * 32 + lane];
            num.x = fmaf(w0, v0.x, num.x); num.y = fmaf(w0, v0.y, num.y);
            num.z = fmaf(w0, v0.z, num.z); num.w = fmaf(w0, v0.w, num.w);
            num.x = fmaf(w1, v1.x, num.x); num.y = fmaf(w1, v1.y, num.y);
            num.z = fmaf(w1, v1.z, num.z); num.w = fmaf(w1, v1.w, num.w);
            num.x = fmaf(w2, v2.x, num.x); num.y = fmaf(w2, v2.y, num.y);
            num.z = fmaf(w2, v2.z, num.z); num.w = fmaf(w2, v2.w, num.w);
            num.x = fmaf(w3, v3.x, num.x); num.y = fmaf(w3, v3.y, num.y);
            num.z = fmaf(w3, v3.z, num.z); num.w = fmaf(w3, v3.w, num.w);
        }
        if (j + 2 <= m) {                     // pair epilogue
            const int   c0 = __shfl(myc,  j + 0, 32);
            const int   c1 = __shfl(myc,  j + 1, 32);
            const float w0 = __shfl(myws, j + 0, 32);
            const float w1 = __shfl(myws, j + 1, 32);
            const float4 v0 = x4[(size_t)c0 * 32 + lane];
            const float4 v1 = x4[(size_t)c1 * 32 + lane];
            num.x = fmaf(w0, v0.x, num.x); num.y = fmaf(w0, v0.y, num.y);
            num.z = fmaf(w0, v0.z, num.z); num.w = fmaf(w0, v0.w, num.w);
            num.x = fmaf(w1, v1.x, num.x); num.y = fmaf(w1, v1.y, num.y);
            num.z = fmaf(w1, v1.z, num.z); num.w = fmaf(w1, v1.w, num.w);
            j += 2;
        }
        if (j < m) {                          // single epilogue
            const int   c0 = __shfl(myc,  j, 32);
            const float w0 = __shfl(myws, j, 32);
            const float4 v0 = x4[(size_t)c0 * 32 + lane];
            num.x = fmaf(w0, v0.x, num.x); num.y = fmaf(w0, v0.y, num.y);
            num.z = fmaf(w0, v0.z, num.z); num.w = fmaf(w0, v0.w, num.w);
        }
    }

    // reduce den across the 32-lane group
    float den = den_l;
    #pragma unroll
    for (int m = 16; m > 0; m >>= 1) den += __shfl_xor(den, m, 64);

    // sign-preserving clamp_abs(den, 1e-10)
    const float sden = (den >= 0.0f) ? 1.0f : -1.0f;
    den = sden * fmaxf(fabsf(den), 1e-10f);
    float4 t;
    t.x = num.x / den; t.y = num.y / den;
    t.z = num.z / den; t.w = num.w / den;

    // group-reduce ||t||^2
    float ss = t.x * t.x + t.y * t.y + t.z * t.z + t.w * t.w;
    #pragma unroll
    for (int m = 16; m > 0; m >>= 1) ss += __shfl_xor(ss, m, 64);

    const float tn = sqrtf(ss);
    const float vn = fmaxf(tn, 1e-15f);               // _safe_norm(two_mean)
    const float ac = fminf(vn, 1.0f - 1e-7f);         // artanh clip (vn >= 0)
    // tanh(0.5*artanh(ac)) = ac / (1 + sqrt(1 - ac^2))  -- exact identity
    const float tanhval = ac / (1.0f + sqrtf(fmaxf(1.0f - ac * ac, 0.0f)));
    const float m_scale = tanhval / vn;               // m = m_scale * t
    const float pn = fmaxf(tanhval * (tn / vn), 1e-15f);
    const float pc = fminf(pn, 1.0f - 1e-7f);
    const float at = 0.5f * __logf((1.0f + pc) / (1.0f - pc));  // atanh via hw log
    const float o_scale = (at / pn) * m_scale;

    float4 o;
    o.x = o_scale * t.x; o.y = o_scale * t.y;
    o.z = o_scale * t.z; o.w = o_scale * t.w;
    out4[(size_t)row * 32 + lane] = o;
}

extern "C" void kernel_launch(void* const* d_in, const int* in_sizes, int n_in,
                              void* d_out, int out_size, void* d_ws, size_t ws_size,
                              hipStream_t stream) {
    const float4* x4   = (const float4*)d_in[0];
    const int*    rows = (const int*)d_in[1];
    const int*    cols = (const int*)d_in[2];
    const float*  vals = (const float*)d_in[3];
    float4* out4 = (float4*)d_out;

    float2* sg = (float2*)d_ws;                         // N float2 = 800 KB
    int* row_ptr = (int*)(sg + N_NODES_C);              // N+1 ints

    node_scale_kernel<<<N_NODES_C / ROWS_PER_BLOCK, 256, 0, stream>>>(x4, sg);
    rowptr_kernel<<<(N_NODES_C + 1 + 255) / 256, 256, 0, stream>>>(rows, row_ptr);
    agg_kernel<<<N_NODES_C / ROWS_PER_BLOCK, 256, 0, stream>>>(x4, sg, cols, vals, row_ptr, out4);
}

// Round 4
// 144.043 us; speedup vs baseline: 1.9322x; 1.1060x over previous
//
#include <hip/hip_runtime.h>
#include <math.h>

#define N_NODES_C 100000
#define N_EDGES_C 600000
#define NODES_PER_BLOCK_K1 8    // kernel1: 32 lanes per node
#define ROWS_PER_BLOCK 16       // kernel3: 16 lanes (one uint4 = 8 bf16 each) per row

// round-to-nearest-even f32 -> bf16 bits
static __device__ __forceinline__ unsigned short f2bf(float f) {
    unsigned int u = __float_as_uint(f);
    u += 0x7fffu + ((u >> 16) & 1u);
    return (unsigned short)(u >> 16);
}

// -------- Kernel 1: per-node scalars + bf16 pre-scaled rows ----------------
// gxb[n,d] = bf16( gamma_n * x_hyp[n,d] )   (25.6 MB working set for the gather)
// gm1[n]   = gamma_n - 1                     (f32, 400 KB)
__global__ void __launch_bounds__(256)
node_scale_kernel(const float4* __restrict__ x4,
                  ushort4* __restrict__ gxb,
                  float* __restrict__ gm1) {
    const int grp  = threadIdx.x >> 5;
    const int lane = threadIdx.x & 31;
    const int node = blockIdx.x * NODES_PER_BLOCK_K1 + grp;

    const float4 v = x4[(size_t)node * 32 + lane];
    float ss = v.x * v.x + v.y * v.y + v.z * v.z + v.w * v.w;
    #pragma unroll
    for (int m = 16; m > 0; m >>= 1) ss += __shfl_xor(ss, m, 64);

    const float un = fmaxf(sqrtf(ss), 1e-15f);        // _safe_norm
    const float e2 = __expf(2.0f * un);               // tanh via hw exp
    const float th = (e2 - 1.0f) / (e2 + 1.0f);
    const float gamma = 2.0f / fmaxf(1.0f - th * th, 1e-15f);
    const float s = gamma * th / un;                  // gx = s * x

    ushort4 o;
    o.x = f2bf(s * v.x);
    o.y = f2bf(s * v.y);
    o.z = f2bf(s * v.z);
    o.w = f2bf(s * v.w);
    gxb[(size_t)node * 32 + lane] = o;
    if (lane == 0) gm1[node] = gamma - 1.0f;
}

// -------- Kernel 2: CSR row_ptr from sorted rows via binary search ---------
__global__ void rowptr_kernel(const int* __restrict__ rows,
                              int* __restrict__ row_ptr) {
    const int i = blockIdx.x * blockDim.x + threadIdx.x;
    if (i > N_NODES_C) return;
    int lo = 0, hi = N_EDGES_C;
    while (lo < hi) {
        int mid = (lo + hi) >> 1;
        if (rows[mid] < i) lo = mid + 1; else hi = mid;
    }
    row_ptr[i] = lo;
}

// unpack 8 bf16 (uint4) and FMA into acc[8]
static __device__ __forceinline__ void fma8(const uint4 u, const float w, float* a) {
    a[0] = fmaf(w, __uint_as_float(u.x << 16),          a[0]);
    a[1] = fmaf(w, __uint_as_float(u.x & 0xffff0000u),  a[1]);
    a[2] = fmaf(w, __uint_as_float(u.y << 16),          a[2]);
    a[3] = fmaf(w, __uint_as_float(u.y & 0xffff0000u),  a[3]);
    a[4] = fmaf(w, __uint_as_float(u.z << 16),          a[4]);
    a[5] = fmaf(w, __uint_as_float(u.z & 0xffff0000u),  a[5]);
    a[6] = fmaf(w, __uint_as_float(u.w << 16),          a[6]);
    a[7] = fmaf(w, __uint_as_float(u.w & 0xffff0000u),  a[7]);
}

// -------- Kernel 3: segment-sum + gyromidpoint + logmap0 -------------------
__global__ void __launch_bounds__(256)
agg_kernel(const uint4* __restrict__ gxb,
           const float* __restrict__ gm1,
           const int* __restrict__ cols,
           const float* __restrict__ vals,
           const int* __restrict__ row_ptr,
           float4* __restrict__ out4) {
    const int grp  = threadIdx.x >> 4;          // 16 groups of 16 lanes
    const int lane = threadIdx.x & 15;
    const int row  = blockIdx.x * ROWS_PER_BLOCK + grp;

    const int e0  = row_ptr[row];
    const int deg = row_ptr[row + 1] - e0;

    float acc[8] = {0.f, 0.f, 0.f, 0.f, 0.f, 0.f, 0.f, 0.f};
    float den_l = 0.0f;

    for (int base = 0; base < deg; base += 16) {
        const int m = min(16, deg - base);
        // cooperative preload: lane l owns edge e0+base+l
        int   myc = 0;
        float myw = 0.0f;
        if (lane < m) {
            const int e = e0 + base + lane;
            myc = cols[e];
            myw = vals[e];
            den_l = fmaf(myw, gm1[myc], den_l);   // den out of the gather loop
        }

        int j = 0;
        for (; j + 4 <= m; j += 4) {              // 4 × 16B gathers in flight
            const int   c0 = __shfl(myc, j + 0, 16);
            const int   c1 = __shfl(myc, j + 1, 16);
            const int   c2 = __shfl(myc, j + 2, 16);
            const int   c3 = __shfl(myc, j + 3, 16);
            const float w0 = __shfl(myw, j + 0, 16);
            const float w1 = __shfl(myw, j + 1, 16);
            const float w2 = __shfl(myw, j + 2, 16);
            const float w3 = __shfl(myw, j + 3, 16);
            const uint4 v0 = gxb[(size_t)c0 * 16 + lane];
            const uint4 v1 = gxb[(size_t)c1 * 16 + lane];
            const uint4 v2 = gxb[(size_t)c2 * 16 + lane];
            const uint4 v3 = gxb[(size_t)c3 * 16 + lane];
            fma8(v0, w0, acc);
            fma8(v1, w1, acc);
            fma8(v2, w2, acc);
            fma8(v3, w3, acc);
        }
        if (j + 2 <= m) {
            const int   c0 = __shfl(myc, j + 0, 16);
            const int   c1 = __shfl(myc, j + 1, 16);
            const float w0 = __shfl(myw, j + 0, 16);
            const float w1 = __shfl(myw, j + 1, 16);
            const uint4 v0 = gxb[(size_t)c0 * 16 + lane];
            const uint4 v1 = gxb[(size_t)c1 * 16 + lane];
            fma8(v0, w0, acc);
            fma8(v1, w1, acc);
            j += 2;
        }
        if (j < m) {
            const int   c0 = __shfl(myc, j, 16);
            const float w0 = __shfl(myw, j, 16);
            const uint4 v0 = gxb[(size_t)c0 * 16 + lane];
            fma8(v0, w0, acc);
        }
    }

    // reduce den across the 16-lane group
    float den = den_l;
    #pragma unroll
    for (int m = 8; m > 0; m >>= 1) den += __shfl_xor(den, m, 16);

    // sign-preserving clamp_abs(den, 1e-10)
    const float sden = (den >= 0.0f) ? 1.0f : -1.0f;
    den = sden * fmaxf(fabsf(den), 1e-10f);

    float t[8];
    float ssl = 0.0f;
    #pragma unroll
    for (int i = 0; i < 8; ++i) { t[i] = acc[i] / den; ssl = fmaf(t[i], t[i], ssl); }

    // group-reduce ||t||^2
    float ss = ssl;
    #pragma unroll
    for (int m = 8; m > 0; m >>= 1) ss += __shfl_xor(ss, m, 16);

    const float tn = sqrtf(ss);
    const float vn = fmaxf(tn, 1e-15f);               // _safe_norm(two_mean)
    const float ac = fminf(vn, 1.0f - 1e-7f);         // artanh clip (vn >= 0)
    // tanh(0.5*artanh(ac)) = ac / (1 + sqrt(1 - ac^2))  -- exact identity
    const float tanhval = ac / (1.0f + sqrtf(fmaxf(1.0f - ac * ac, 0.0f)));
    const float m_scale = tanhval / vn;               // m = m_scale * t
    const float pn = fmaxf(tanhval * (tn / vn), 1e-15f);
    const float pc = fminf(pn, 1.0f - 1e-7f);
    const float at = 0.5f * __logf((1.0f + pc) / (1.0f - pc));  // atanh via hw log
    const float o_scale = (at / pn) * m_scale;

    float4 o0, o1;
    o0.x = o_scale * t[0]; o0.y = o_scale * t[1];
    o0.z = o_scale * t[2]; o0.w = o_scale * t[3];
    o1.x = o_scale * t[4]; o1.y = o_scale * t[5];
    o1.z = o_scale * t[6]; o1.w = o_scale * t[7];
    out4[(size_t)row * 32 + lane * 2 + 0] = o0;
    out4[(size_t)row * 32 + lane * 2 + 1] = o1;
}

extern "C" void kernel_launch(void* const* d_in, const int* in_sizes, int n_in,
                              void* d_out, int out_size, void* d_ws, size_t ws_size,
                              hipStream_t stream) {
    const float4* x4   = (const float4*)d_in[0];
    const int*    rows = (const int*)d_in[1];
    const int*    cols = (const int*)d_in[2];
    const float*  vals = (const float*)d_in[3];
    float4* out4 = (float4*)d_out;

    // workspace layout
    ushort4* gxb = (ushort4*)d_ws;                          // N*128 bf16 = 25.6 MB
    float* gm1   = (float*)((char*)d_ws + (size_t)N_NODES_C * 128 * 2);
    int* row_ptr = (int*)(gm1 + N_NODES_C);

    node_scale_kernel<<<N_NODES_C / NODES_PER_BLOCK_K1, 256, 0, stream>>>(x4, gxb, gm1);
    rowptr_kernel<<<(N_NODES_C + 1 + 255) / 256, 256, 0, stream>>>(rows, row_ptr);
    agg_kernel<<<N_NODES_C / ROWS_PER_BLOCK, 256, 0, stream>>>((const uint4*)gxb, gm1, cols, vals, row_ptr, out4);
}

// Round 5
// 132.355 us; speedup vs baseline: 2.1028x; 1.0883x over previous
//
#include <hip/hip_runtime.h>
#include <math.h>

#define N_NODES_C 100000
#define N_EDGES_C 600000
#define NODES_PER_BLOCK_K1 8    // kernel1: 32 lanes per node
#define ROWS_PER_BLOCK 16       // kernel3: 16 lanes (uint2 = 8 int8 each) per row

// -------- Kernel 1: per-node scalars + int8 pre-scaled rows + fused rowptr --
// q[n,d]  = int8( round( gx[n,d] / scale_n ) ),  scale_n = max_d |gx[n,d]| / 127
// sg[n]   = { scale_n, gamma_n - 1 }
// row_ptr = CSR offsets from sorted rows (fused binary search)
__global__ void __launch_bounds__(256)
node_scale_kernel(const float4* __restrict__ x4,
                  const int* __restrict__ rows,
                  unsigned int* __restrict__ gxq,
                  float2* __restrict__ sg,
                  int* __restrict__ row_ptr) {
    // fused CSR row_ptr (first 391 blocks do the search; independent index domain)
    const int gid = blockIdx.x * blockDim.x + threadIdx.x;
    if (gid <= N_NODES_C) {
        int lo = 0, hi = N_EDGES_C;
        while (lo < hi) {
            int mid = (lo + hi) >> 1;
            if (rows[mid] < gid) lo = mid + 1; else hi = mid;
        }
        row_ptr[gid] = lo;
    }

    const int grp  = threadIdx.x >> 5;
    const int lane = threadIdx.x & 31;
    const int node = blockIdx.x * NODES_PER_BLOCK_K1 + grp;

    const float4 v = x4[(size_t)node * 32 + lane];
    float ss = v.x * v.x + v.y * v.y + v.z * v.z + v.w * v.w;
    #pragma unroll
    for (int m = 16; m > 0; m >>= 1) ss += __shfl_xor(ss, m, 64);

    const float un = fmaxf(sqrtf(ss), 1e-15f);        // _safe_norm
    const float e2 = __expf(2.0f * un);               // tanh via hw exp
    const float th = (e2 - 1.0f) / (e2 + 1.0f);
    const float gamma = 2.0f / fmaxf(1.0f - th * th, 1e-15f);
    const float s = gamma * th / un;                  // gx = s * x

    float4 g;
    g.x = s * v.x; g.y = s * v.y; g.z = s * v.z; g.w = s * v.w;

    // per-node max |gx_d| across the 32 lanes (4 dims each)
    float amax = fmaxf(fmaxf(fabsf(g.x), fabsf(g.y)), fmaxf(fabsf(g.z), fabsf(g.w)));
    #pragma unroll
    for (int m = 16; m > 0; m >>= 1) amax = fmaxf(amax, __shfl_xor(amax, m, 64));

    const float inv = (amax > 0.0f) ? (127.0f / amax) : 0.0f;
    int q0 = (int)rintf(g.x * inv);
    int q1 = (int)rintf(g.y * inv);
    int q2 = (int)rintf(g.z * inv);
    int q3 = (int)rintf(g.w * inv);
    q0 = min(max(q0, -127), 127); q1 = min(max(q1, -127), 127);
    q2 = min(max(q2, -127), 127); q3 = min(max(q3, -127), 127);
    const unsigned int packed = (q0 & 0xff) | ((q1 & 0xff) << 8) |
                                ((q2 & 0xff) << 16) | ((q3 & 0xff) << 24);
    gxq[(size_t)node * 32 + lane] = packed;           // dims [4*lane, 4*lane+4)
    if (lane == 0) sg[node] = make_float2(amax / 127.0f, gamma - 1.0f);
}

// unpack 8 int8 (uint2, LSB-first) and FMA with weight ws = w*scale
static __device__ __forceinline__ void fma8i(const uint2 u, const float ws, float* a) {
    a[0] = fmaf(ws, (float)((int)(u.x << 24) >> 24), a[0]);
    a[1] = fmaf(ws, (float)((int)(u.x << 16) >> 24), a[1]);
    a[2] = fmaf(ws, (float)((int)(u.x <<  8) >> 24), a[2]);
    a[3] = fmaf(ws, (float)((int) u.x        >> 24), a[3]);
    a[4] = fmaf(ws, (float)((int)(u.y << 24) >> 24), a[4]);
    a[5] = fmaf(ws, (float)((int)(u.y << 16) >> 24), a[5]);
    a[6] = fmaf(ws, (float)((int)(u.y <<  8) >> 24), a[6]);
    a[7] = fmaf(ws, (float)((int) u.y        >> 24), a[7]);
}

// -------- Kernel 2: segment-sum + gyromidpoint + logmap0 -------------------
__global__ void __launch_bounds__(256)
agg_kernel(const uint2* __restrict__ gxq,
           const float2* __restrict__ sg,
           const int* __restrict__ cols,
           const float* __restrict__ vals,
           const int* __restrict__ row_ptr,
           float4* __restrict__ out4) {
    const int grp  = threadIdx.x >> 4;          // 16 groups of 16 lanes
    const int lane = threadIdx.x & 15;
    const int row  = blockIdx.x * ROWS_PER_BLOCK + grp;

    const int e0  = row_ptr[row];
    const int deg = row_ptr[row + 1] - e0;

    float acc[8] = {0.f, 0.f, 0.f, 0.f, 0.f, 0.f, 0.f, 0.f};
    float den_l = 0.0f;

    for (int base = 0; base < deg; base += 16) {
        const int m = min(16, deg - base);
        // cooperative preload: lane l owns edge e0+base+l
        int   myc  = 0;
        float myws = 0.0f;
        if (lane < m) {
            const int e = e0 + base + lane;
            myc = cols[e];
            const float w = vals[e];
            const float2 s2 = sg[myc];          // {scale, gamma-1}, L2-resident
            myws = w * s2.x;                    // weight * dequant scale
            den_l = fmaf(w, s2.y, den_l);       // den out of the gather loop
        }

        int j = 0;
        for (; j + 4 <= m; j += 4) {            // 4 × 8B gathers in flight
            const int   c0 = __shfl(myc,  j + 0, 16);
            const int   c1 = __shfl(myc,  j + 1, 16);
            const int   c2 = __shfl(myc,  j + 2, 16);
            const int   c3 = __shfl(myc,  j + 3, 16);
            const float w0 = __shfl(myws, j + 0, 16);
            const float w1 = __shfl(myws, j + 1, 16);
            const float w2 = __shfl(myws, j + 2, 16);
            const float w3 = __shfl(myws, j + 3, 16);
            const uint2 v0 = gxq[(size_t)c0 * 16 + lane];
            const uint2 v1 = gxq[(size_t)c1 * 16 + lane];
            const uint2 v2 = gxq[(size_t)c2 * 16 + lane];
            const uint2 v3 = gxq[(size_t)c3 * 16 + lane];
            fma8i(v0, w0, acc);
            fma8i(v1, w1, acc);
            fma8i(v2, w2, acc);
            fma8i(v3, w3, acc);
        }
        if (j + 2 <= m) {
            const int   c0 = __shfl(myc,  j + 0, 16);
            const int   c1 = __shfl(myc,  j + 1, 16);
            const float w0 = __shfl(myws, j + 0, 16);
            const float w1 = __shfl(myws, j + 1, 16);
            const uint2 v0 = gxq[(size_t)c0 * 16 + lane];
            const uint2 v1 = gxq[(size_t)c1 * 16 + lane];
            fma8i(v0, w0, acc);
            fma8i(v1, w1, acc);
            j += 2;
        }
        if (j < m) {
            const int   c0 = __shfl(myc,  j, 16);
            const float w0 = __shfl(myws, j, 16);
            const uint2 v0 = gxq[(size_t)c0 * 16 + lane];
            fma8i(v0, w0, acc);
        }
    }

    // reduce den across the 16-lane group
    float den = den_l;
    #pragma unroll
    for (int m = 8; m > 0; m >>= 1) den += __shfl_xor(den, m, 16);

    // sign-preserving clamp_abs(den, 1e-10)
    const float sden = (den >= 0.0f) ? 1.0f : -1.0f;
    den = sden * fmaxf(fabsf(den), 1e-10f);

    float t[8];
    float ssl = 0.0f;
    #pragma unroll
    for (int i = 0; i < 8; ++i) { t[i] = acc[i] / den; ssl = fmaf(t[i], t[i], ssl); }

    // group-reduce ||t||^2
    float ss = ssl;
    #pragma unroll
    for (int m = 8; m > 0; m >>= 1) ss += __shfl_xor(ss, m, 16);

    const float tn = sqrtf(ss);
    const float vn = fmaxf(tn, 1e-15f);               // _safe_norm(two_mean)
    const float ac = fminf(vn, 1.0f - 1e-7f);         // artanh clip (vn >= 0)
    // tanh(0.5*artanh(ac)) = ac / (1 + sqrt(1 - ac^2))  -- exact identity
    const float tanhval = ac / (1.0f + sqrtf(fmaxf(1.0f - ac * ac, 0.0f)));
    const float m_scale = tanhval / vn;               // m = m_scale * t
    const float pn = fmaxf(tanhval * (tn / vn), 1e-15f);
    const float pc = fminf(pn, 1.0f - 1e-7f);
    const float at = 0.5f * __logf((1.0f + pc) / (1.0f - pc));  // atanh via hw log
    const float o_scale = (at / pn) * m_scale;

    float4 o0, o1;
    o0.x = o_scale * t[0]; o0.y = o_scale * t[1];
    o0.z = o_scale * t[2]; o0.w = o_scale * t[3];
    o1.x = o_scale * t[4]; o1.y = o_scale * t[5];
    o1.z = o_scale * t[6]; o1.w = o_scale * t[7];
    out4[(size_t)row * 32 + lane * 2 + 0] = o0;
    out4[(size_t)row * 32 + lane * 2 + 1] = o1;
}

extern "C" void kernel_launch(void* const* d_in, const int* in_sizes, int n_in,
                              void* d_out, int out_size, void* d_ws, size_t ws_size,
                              hipStream_t stream) {
    const float4* x4   = (const float4*)d_in[0];
    const int*    rows = (const int*)d_in[1];
    const int*    cols = (const int*)d_in[2];
    const float*  vals = (const float*)d_in[3];
    float4* out4 = (float4*)d_out;

    // workspace layout
    unsigned int* gxq = (unsigned int*)d_ws;                      // N*128 int8 = 12.8 MB
    float2* sg  = (float2*)((char*)d_ws + (size_t)N_NODES_C * 128);   // 800 KB
    int* row_ptr = (int*)(sg + N_NODES_C);                        // 400 KB

    node_scale_kernel<<<N_NODES_C / NODES_PER_BLOCK_K1, 256, 0, stream>>>(
        x4, rows, gxq, sg, row_ptr);
    agg_kernel<<<N_NODES_C / ROWS_PER_BLOCK, 256, 0, stream>>>(
        (const uint2*)gxq, sg, cols, vals, row_ptr, out4);
}